// Round 9
// baseline (224.830 us; speedup 1.0000x reference)
//
#include <hip/hip_runtime.h>
#include <hip/hip_bf16.h>
#include <cstddef>
#include <cstdint>

// Problem dims
constexpr int Nn = 4096;
constexpr int Ss = 128;
constexpr int Ff = 128;
constexpr int Dd = 256;
constexpr float EPSV = 1e-8f;

// d_out layout (floats): h_o [N*D], C_new [N*S*F], k [N*F], r [N*F]
constexpr size_t HO_OFF = 0;
constexpr size_t C_OFF  = (size_t)Nn * Dd;
constexpr size_t K_OFF  = C_OFF + (size_t)Nn * Ss * Ff;
constexpr size_t R_OFF  = K_OFF + (size_t)Nn * Ff;

typedef __attribute__((ext_vector_type(4))) float f4v;
typedef __attribute__((ext_vector_type(8))) short bh8;
typedef __attribute__((ext_vector_type(4))) short bh4;

// bf16 weight pack offsets in ws (units: shorts)
constexpr int WK_O  = 0;        // Wk   128x256
constexpr int WHH_O = 32768;    // Whh  768x256
constexpr int WIH_O = 229376;   // Wih  768x128
constexpr int WEV_O = 327680;   // [We;Wv] 256x256
constexpr int W_TOT = 393216;

__device__ __forceinline__ float sigmf(float x) { return 1.0f / (1.0f + __expf(-x)); }

__device__ __forceinline__ short f2bf(float x) {
    __hip_bfloat16 h = __float2bfloat16(x);   // RNE
    return *reinterpret_cast<short*>(&h);
}

// XOR swizzle: spread 16B k-slots of row r across banks. Row strides 512B / 256B.
__device__ __forceinline__ int swzH(int row, int kb) { return row * 512 + (kb ^ ((row & 7) << 4)); }
__device__ __forceinline__ int swzR(int row, int kb) { return row * 256 + (kb ^ ((row & 7) << 4)); }

__device__ __forceinline__ f4v mfma16(bh8 a, bh8 b, f4v c) {
    return __builtin_amdgcn_mfma_f32_16x16x32_bf16(a, b, c, 0, 0, 0);
}

// ---------------------------------------------------------------------------
// Prep: convert all weights to bf16, packed row-major into ws.
// ---------------------------------------------------------------------------
__global__ __launch_bounds__(256) void prep_weights(
    const float* __restrict__ Wk, const float* __restrict__ Whh,
    const float* __restrict__ Wih, const float* __restrict__ We,
    const float* __restrict__ Wv, short* __restrict__ out)
{
    int id = blockIdx.x * 256 + threadIdx.x;   // grid covers W_TOT exactly
    float v;
    if      (id < WHH_O) v = Wk[id - WK_O];
    else if (id < WIH_O) v = Whh[id - WHH_O];
    else if (id < WEV_O) v = Wih[id - WIH_O];
    else if (id < WEV_O + 32768) v = We[id - WEV_O];
    else v = Wv[id - WEV_O - 32768];
    out[id] = f2bf(v);
}

// ---------------------------------------------------------------------------
// K1: per 8-row block: k = h@Wk^T + bk (MFMA), beta, gh = h@Whh^T (no bias).
// ---------------------------------------------------------------------------
__global__ __launch_bounds__(512, 2) void k1_pre(
    const float* __restrict__ h_prev, const short* __restrict__ WB,
    const float* __restrict__ Wb, const float* __restrict__ bb,
    const float* __restrict__ bk,
    float* __restrict__ kout, float* __restrict__ beta_out,
    float* __restrict__ gh_out)
{
    __shared__ float sH[8][256];
    __shared__ __align__(16) short sHb[16 * 256];

    const int t  = threadIdx.x;
    const int l  = t & 63;
    const int wv = t >> 6;
    const int nb = blockIdx.x * 8;
    char* hb = (char*)sHb;

    const short* WkB  = WB + WK_O;
    const short* WhhB = WB + WHH_O;

    // P0: load h, build swizzled bf16 tile, zero pad rows
    {
        const int f = t * 4, row = f >> 8, col = f & 255;
        float4 hv = *(const float4*)(h_prev + (size_t)(nb + row) * Dd + col);
        *(float4*)&sH[row][col] = hv;
        bh4 hb4 = { f2bf(hv.x), f2bf(hv.y), f2bf(hv.z), f2bf(hv.w) };
        *(bh4*)(hb + swzH(row, col * 2)) = hb4;
        *(int64_t*)(hb + 4096 + t * 8) = 0;   // rows 8..15
    }
    __syncthreads();

    const int fr = l & 15, kq = l >> 4, rbase = kq * 4;

    // k GEMM
    {
        const int colg = wv * 16 + fr;
        f4v acc = {0.f, 0.f, 0.f, 0.f};
#pragma unroll
        for (int kc = 0; kc < 8; ++kc) {
            bh8 a = *(const bh8*)(hb + swzH(fr, kc * 64 + kq * 16));
            bh8 b = *(const bh8*)(WkB + (size_t)colg * 256 + kc * 32 + kq * 8);
            acc = mfma16(a, b, acc);
        }
        if (rbase < 8) {
            const float bs = bk[colg];
#pragma unroll
            for (int rg = 0; rg < 4; ++rg)
                kout[(size_t)(nb + rbase + rg) * Ff + colg] = acc[rg] + bs;
        }
    }

    // beta (wave wv -> row wv)
    {
        float4 hv = *(const float4*)&sH[wv][l * 4];
        float4 wb4 = *(const float4*)(Wb + l * 4);
        float bp = hv.x * wb4.x + hv.y * wb4.y + hv.z * wb4.z + hv.w * wb4.w;
#pragma unroll
        for (int o = 32; o > 0; o >>= 1) bp += __shfl_xor(bp, o);
        if (l == 0) {
            bp += bb[0];
            beta_out[nb + wv] = ((bp > 20.0f) ? bp : log1pf(__expf(bp))) + 1.0f;
        }
    }

    // gh GEMM (no bias; K3 adds biases)
    {
#pragma unroll
        for (int i = 0; i < 6; ++i) {
            const int colg = i * 128 + wv * 16 + fr;
            f4v g = {0.f, 0.f, 0.f, 0.f};
#pragma unroll
            for (int kc = 0; kc < 8; ++kc) {
                bh8 a = *(const bh8*)(hb + swzH(fr, kc * 64 + kq * 16));
                bh8 b = *(const bh8*)(WhhB + (size_t)colg * 256 + kc * 32 + kq * 8);
                g = mfma16(a, b, g);
            }
            if (rbase < 8) {
#pragma unroll
                for (int rg = 0; rg < 4; ++rg)
                    gh_out[(size_t)(nb + rbase + rg) * 768 + colg] = g[rg];
            }
        }
    }
}

// ---------------------------------------------------------------------------
// K2: attention, one row per block (4096 blocks x 256 thr). Single pass over
// C with fixed-shift softmax p = exp(beta*(cos-1)); writes normalized w and r.
// ---------------------------------------------------------------------------
__global__ __launch_bounds__(256, 6) void k2_attn(
    const float* __restrict__ C, const float* __restrict__ kin,
    const float* __restrict__ beta_in,
    float* __restrict__ w_out, float* __restrict__ r_out)
{
    __shared__ float sk[128];
    __shared__ float sSc[128];
    __shared__ float sred[4];
    __shared__ float sr4[4][128];

    const int n    = blockIdx.x;
    const int t    = threadIdx.x;
    const int lane = t & 63;
    const int wid  = t >> 6;
    const float* Cn = C + (size_t)n * (Ss * Ff);

    if (t < 128) sk[t] = kin[(size_t)n * Ff + t];
    __syncthreads();

    // knorm (each wave computes redundantly; butterfly over 64)
    float kv0 = sk[lane], kv1 = sk[64 + lane];
    float ks = kv0 * kv0 + kv1 * kv1;
#pragma unroll
    for (int o = 32; o > 0; o >>= 1) ks += __shfl_xor(ks, o);
    const float knorm = fmaxf(sqrtf(ks), EPSV);
    const float beta  = beta_in[n];

    const int sub = lane >> 5, fl = lane & 31, f4 = fl * 4;
    const float4 kreg = *(const float4*)&sk[f4];
    float lsum = 0.0f;
    f4v racc = {0.f, 0.f, 0.f, 0.f};

#pragma unroll 8
    for (int it = 0; it < 16; ++it) {
        const int s = wid * 32 + it * 2 + sub;
        const f4v c4 = *(const f4v*)(Cn + (size_t)s * Ff + f4);
        float d = c4.x * kreg.x + c4.y * kreg.y + c4.z * kreg.z + c4.w * kreg.w;
        float q = c4.x * c4.x + c4.y * c4.y + c4.z * c4.z + c4.w * c4.w;
#pragma unroll
        for (int o = 16; o > 0; o >>= 1) {
            d += __shfl_xor(d, o);
            q += __shfl_xor(q, o);
        }
        const float cn = fmaxf(sqrtf(q), EPSV);
        const float x = d / (cn * knorm) * beta;   // x <= beta (cosine <= 1)
        const float p = __expf(x - beta);
        if (fl == 0) sSc[s] = p;
        lsum += p;
        racc += p * c4;
    }
    // combine the two 32-lane subgroups of each wave
    lsum += __shfl_xor(lsum, 32);
    racc.x += __shfl_xor(racc.x, 32);
    racc.y += __shfl_xor(racc.y, 32);
    racc.z += __shfl_xor(racc.z, 32);
    racc.w += __shfl_xor(racc.w, 32);
    if (lane == 0) sred[wid] = lsum;
    if (sub == 0) *(f4v*)&sr4[wid][f4] = racc;
    __syncthreads();

    const float iL = 1.0f / (sred[0] + sred[1] + sred[2] + sred[3]);
    if (t < 128) w_out[(size_t)n * Ss + t] = sSc[t] * iL;
    if (t < 32) {
        f4v rr = *(f4v*)&sr4[0][t * 4];
#pragma unroll
        for (int g = 1; g < 4; ++g) rr += *(f4v*)&sr4[g][t * 4];
        rr *= iL;
        *(f4v*)(r_out + (size_t)n * Ff + t * 4) = rr;
    }
}

// ---------------------------------------------------------------------------
// K3: per 8-row block: gi = r@Wih^T (MFMA), gates in regs (gh from ws) -> h_o,
// then [e|v] = sig/lin(h_o@[We;Wv]^T) (MFMA) -> ev_out.
// ---------------------------------------------------------------------------
__global__ __launch_bounds__(512, 2) void k3_post(
    const float* __restrict__ h_prev, const short* __restrict__ WB,
    const float* __restrict__ gh_in, const float* __restrict__ rin,
    const float* __restrict__ bhh, const float* __restrict__ bih,
    const float* __restrict__ be, const float* __restrict__ bv,
    float* __restrict__ ho, float* __restrict__ ev_out)
{
    __shared__ float sH[8][256];                  // h_prev fp32
    __shared__ __align__(16) short sHb[16 * 256]; // h_o bf16 swizzled
    __shared__ __align__(16) short sRb[16 * 128]; // r bf16 swizzled

    const int t  = threadIdx.x;
    const int l  = t & 63;
    const int wv = t >> 6;
    const int nb = blockIdx.x * 8;
    char* hb = (char*)sHb;
    char* rb = (char*)sRb;

    const short* WihB = WB + WIH_O;
    const short* WevB = WB + WEV_O;

    // P0
    {
        const int row = t >> 6, col = (t & 63) * 4;
        *(float4*)&sH[row][col] = *(const float4*)(h_prev + (size_t)(nb + row) * Dd + col);
        if (t < 256) {
            const int rr = t >> 5, rc = (t & 31) * 4;
            float4 rv = *(const float4*)(rin + (size_t)(nb + rr) * Ff + rc);
            bh4 rb4 = { f2bf(rv.x), f2bf(rv.y), f2bf(rv.z), f2bf(rv.w) };
            *(bh4*)(rb + swzR(rr, rc * 2)) = rb4;
        } else {
            const int tt = t - 256;
            *(int64_t*)(rb + 2048 + tt * 8) = 0;     // sRb rows 8..15
            *(int4*)(hb + 4096 + tt * 16) = int4{0, 0, 0, 0};   // sHb rows 8..15
        }
    }
    __syncthreads();

    const int fr = l & 15, kq = l >> 4, rbase = kq * 4;

    // gi GEMM + gates
    {
        f4v aI[6];
#pragma unroll
        for (int i = 0; i < 6; ++i) {
            const int colg = i * 128 + wv * 16 + fr;
            f4v ii = {0.f, 0.f, 0.f, 0.f};
#pragma unroll
            for (int kc = 0; kc < 4; ++kc) {
                bh8 a = *(const bh8*)(rb + swzR(fr, kc * 64 + kq * 16));
                bh8 b = *(const bh8*)(WihB + (size_t)colg * 128 + kc * 32 + kq * 8);
                ii = mfma16(a, b, ii);
            }
            aI[i] = ii;
        }

        float hoReg[2][4];
        if (rbase < 8) {
            float aG[6][4];
#pragma unroll
            for (int i = 0; i < 6; ++i) {
                const int colg = i * 128 + wv * 16 + fr;
#pragma unroll
                for (int rg = 0; rg < 4; ++rg)
                    aG[i][rg] = gh_in[(size_t)(nb + rbase + rg) * 768 + colg];
            }
#pragma unroll
            for (int dp = 0; dp < 2; ++dp) {
                const int d = dp * 128 + wv * 16 + fr;
                const float br  = bhh[d] + bih[d];
                const float bz  = bhh[256 + d] + bih[256 + d];
                const float bhn = bhh[512 + d];
                const float bin = bih[512 + d];
#pragma unroll
                for (int rg = 0; rg < 4; ++rg) {
                    const float rgt = sigmf(aG[dp][rg] + aI[dp][rg] + br);
                    const float z   = sigmf(aG[2 + dp][rg] + aI[2 + dp][rg] + bz);
                    const float nn  = tanhf(aI[4 + dp][rg] + bin + rgt * (aG[4 + dp][rg] + bhn));
                    const float hp  = sH[rbase + rg][d];
                    hoReg[dp][rg] = (1.0f - z) * nn + z * hp;
                }
            }
        }
        __syncthreads();   // sHb pads settled; now fill rows 0..7 with h_o
        if (rbase < 8) {
#pragma unroll
            for (int dp = 0; dp < 2; ++dp) {
                const int d = dp * 128 + wv * 16 + fr;
#pragma unroll
                for (int rg = 0; rg < 4; ++rg) {
                    const int row = rbase + rg;
                    const float o = hoReg[dp][rg];
                    ho[(size_t)(nb + row) * Dd + d] = o;
                    *(short*)(hb + row * 512 + ((d * 2) ^ ((row & 7) << 4))) = f2bf(o);
                }
            }
        }
    }
    __syncthreads();

    // EV GEMM
    {
#pragma unroll
        for (int i = 0; i < 2; ++i) {
            const int colg = i * 128 + wv * 16 + fr;
            f4v acc = {0.f, 0.f, 0.f, 0.f};
#pragma unroll
            for (int kc = 0; kc < 8; ++kc) {
                bh8 a = *(const bh8*)(hb + swzH(fr, kc * 64 + kq * 16));
                bh8 b = *(const bh8*)(WevB + (size_t)colg * 256 + kc * 32 + kq * 8);
                acc = mfma16(a, b, acc);
            }
            if (rbase < 8) {
                const float bs = (colg < 128) ? be[colg] : bv[colg - 128];
#pragma unroll
                for (int rg = 0; rg < 4; ++rg) {
                    float x = acc[rg] + bs;
                    if (colg < 128) x = sigmf(x);
                    ev_out[(size_t)(nb + rbase + rg) * 256 + colg] = x;
                }
            }
        }
    }
}

// ---------------------------------------------------------------------------
// K4: C_new = C*(1 - w*e) + w*v. Grid-stride, 4 independent load windows,
// normal C loads (L3-hot from K2), NT stores.
// ---------------------------------------------------------------------------
__global__ __launch_bounds__(256, 4) void k4_update(
    const float* __restrict__ C, const float* __restrict__ w,
    const float* __restrict__ ev, float* __restrict__ Cnew)
{
    const size_t stride = (size_t)2048 * 256;
    const size_t i0 = (size_t)blockIdx.x * 256 + threadIdx.x;
#pragma unroll 1
    for (int rep = 0; rep < 32; rep += 4) {
        f4v c[4], e4[4], v4[4];
        float wsc[4];
#pragma unroll
        for (int j = 0; j < 4; ++j) {
            const size_t i = i0 + (size_t)(rep + j) * stride;
            const int n = (int)(i >> 12);
            const int rem = (int)(i & 4095);
            const int s = rem >> 5;
            const int f4 = (rem & 31) * 4;
            c[j]   = *(const f4v*)(C + i * 4);
            wsc[j] = w[(size_t)n * Ss + s];
            e4[j]  = *(const f4v*)(ev + (size_t)n * 256 + f4);
            v4[j]  = *(const f4v*)(ev + (size_t)n * 256 + 128 + f4);
        }
#pragma unroll
        for (int j = 0; j < 4; ++j) {
            const size_t i = i0 + (size_t)(rep + j) * stride;
            f4v o = c[j] * (1.0f - wsc[j] * e4[j]) + wsc[j] * v4[j];
            __builtin_nontemporal_store(o, (f4v*)(Cnew + i * 4));
        }
    }
}

// ---------------------------------------------------------------------------
extern "C" void kernel_launch(void* const* d_in, const int* in_sizes, int n_in,
                              void* d_out, int out_size, void* d_ws, size_t ws_size,
                              hipStream_t stream)
{
    const float* h_prev = (const float*)d_in[0];
    const float* C      = (const float*)d_in[1];
    const float* Wk     = (const float*)d_in[2];
    const float* bk     = (const float*)d_in[3];
    const float* Wb     = (const float*)d_in[4];
    const float* bb     = (const float*)d_in[5];
    const float* We     = (const float*)d_in[6];
    const float* be     = (const float*)d_in[7];
    const float* Wv     = (const float*)d_in[8];
    const float* bv     = (const float*)d_in[9];
    const float* Wih    = (const float*)d_in[10];
    const float* Whh    = (const float*)d_in[11];
    const float* bih    = (const float*)d_in[12];
    const float* bhh    = (const float*)d_in[13];

    float* out  = (float*)d_out;
    float* ho   = out + HO_OFF;
    float* Cnew = out + C_OFF;
    float* kbuf = out + K_OFF;
    float* rbuf = out + R_OFF;

    short* wsB = (short*)d_ws;
    float* wsF     = (float*)(wsB + W_TOT);
    float* ws_gh   = wsF;                          // N*768
    float* ws_beta = ws_gh + (size_t)Nn * 768;     // N
    float* ws_w    = ws_beta + Nn;                 // N*128
    float* ws_ev   = ws_w + (size_t)Nn * Ss;       // N*256

    prep_weights<<<W_TOT / 256, 256, 0, stream>>>(Wk, Whh, Wih, We, Wv, wsB);

    k1_pre<<<Nn / 8, 512, 0, stream>>>(h_prev, wsB, Wb, bb, bk,
                                       kbuf, ws_beta, ws_gh);

    k2_attn<<<Nn, 256, 0, stream>>>(C, kbuf, ws_beta, ws_w, rbuf);

    k3_post<<<Nn / 8, 512, 0, stream>>>(h_prev, wsB, ws_gh, rbuf,
                                        bhh, bih, be, bv, ho, ws_ev);

    k4_update<<<2048, 256, 0, stream>>>(C, ws_w, ws_ev, Cnew);
}

// Round 10
// 221.132 us; speedup vs baseline: 1.0167x; 1.0167x over previous
//
#include <hip/hip_runtime.h>
#include <hip/hip_bf16.h>
#include <cstddef>
#include <cstdint>

// Problem dims
constexpr int Nn = 4096;
constexpr int Ss = 128;
constexpr int Ff = 128;
constexpr int Dd = 256;
constexpr float EPSV = 1e-8f;

// d_out layout (floats): h_o [N*D], C_new [N*S*F], k [N*F], r [N*F]
constexpr size_t HO_OFF = 0;
constexpr size_t C_OFF  = (size_t)Nn * Dd;
constexpr size_t K_OFF  = C_OFF + (size_t)Nn * Ss * Ff;
constexpr size_t R_OFF  = K_OFF + (size_t)Nn * Ff;

typedef __attribute__((ext_vector_type(4))) float f4v;
typedef __attribute__((ext_vector_type(8))) short bh8;
typedef __attribute__((ext_vector_type(4))) short bh4;

// bf16 weight pack offsets in ws (units: shorts)
constexpr int WK_O  = 0;        // Wk   128x256
constexpr int WHH_O = 32768;    // Whh  768x256
constexpr int WIH_O = 229376;   // Wih  768x128
constexpr int WEV_O = 327680;   // [We;Wv] 256x256
constexpr int W_TOT = 393216;

__device__ __forceinline__ float sigmf(float x) { return 1.0f / (1.0f + __expf(-x)); }

__device__ __forceinline__ short f2bf(float x) {
    __hip_bfloat16 h = __float2bfloat16(x);   // RNE
    return *reinterpret_cast<short*>(&h);
}

// XOR swizzle: spread 16B k-slots of row r across banks. Row strides 512B / 256B.
__device__ __forceinline__ int swzH(int row, int kb) { return row * 512 + (kb ^ ((row & 7) << 4)); }
__device__ __forceinline__ int swzR(int row, int kb) { return row * 256 + (kb ^ ((row & 7) << 4)); }

__device__ __forceinline__ f4v mfma16(bh8 a, bh8 b, f4v c) {
    return __builtin_amdgcn_mfma_f32_16x16x32_bf16(a, b, c, 0, 0, 0);
}

// ---------------------------------------------------------------------------
// Prep: convert all weights to bf16, packed row-major into ws.
// ---------------------------------------------------------------------------
__global__ __launch_bounds__(256) void prep_weights(
    const float* __restrict__ Wk, const float* __restrict__ Whh,
    const float* __restrict__ Wih, const float* __restrict__ We,
    const float* __restrict__ Wv, short* __restrict__ out)
{
    int id = blockIdx.x * 256 + threadIdx.x;   // grid covers W_TOT exactly
    float v;
    if      (id < WHH_O) v = Wk[id - WK_O];
    else if (id < WIH_O) v = Whh[id - WHH_O];
    else if (id < WEV_O) v = Wih[id - WIH_O];
    else if (id < WEV_O + 32768) v = We[id - WEV_O];
    else v = Wv[id - WEV_O - 32768];
    out[id] = f2bf(v);
}

// ---------------------------------------------------------------------------
// Mega kernel: 512 blocks x 512 threads; block handles 8 rows, wave w = row w.
// LDS dieted to 36 KB -> 3 blocks/CU (24 waves) vs R5-R8's 2. More co-resident
// blocks = more independent phase streams per CU (memory || MFMA || VALU).
//  P0 load h (fp32 + swizzled bf16, zero pads)
//  P1 k = h@Wk^T + bk                          [MFMA]
//  P2 one pass over C: fixed-shift softmax p=exp(x-beta), r online (unroll 4)
//  P3 gh/gi MFMAs in TWO dp-passes (6 live accs), gates in regs -> h_o
//  P5 [e|v] = sig/lin(h_o@[We;Wv]^T)           [MFMA]
//  P6 C_new = C*(1-w*e)+w*v (C re-read L2/L3-hot), NT stores
// ---------------------------------------------------------------------------
__global__ __launch_bounds__(512, 6) void mega_kernel(
    const float* __restrict__ C, const float* __restrict__ h_prev,
    const short* __restrict__ WB,
    const float* __restrict__ Wb, const float* __restrict__ bb,
    const float* __restrict__ bk, const float* __restrict__ bhh,
    const float* __restrict__ bih, const float* __restrict__ be,
    const float* __restrict__ bv,
    float* __restrict__ ho, float* __restrict__ Cnew,
    float* __restrict__ kout, float* __restrict__ rout)
{
    __shared__ float sH[8][256];                  // h_prev fp32            8 KB
    __shared__ __align__(16) short sHb[16 * 256]; // h/h_o bf16 swizzled    8 KB
    __shared__ __align__(16) short sRb[16 * 128]; // r bf16 swizzled        4 KB
    __shared__ float sK[8][128];                  //                        4 KB
    __shared__ float sSc[8][128];                 // p per (row,s)          4 KB
    __shared__ float sEV[8][256];                 // e | v                  8 KB
                                                  // total 36 KB -> 3 blk/CU

    const int t  = threadIdx.x;
    const int l  = t & 63;
    const int wv = t >> 6;
    const int nb = blockIdx.x * 8;
    char* hb = (char*)sHb;
    char* rb = (char*)sRb;

    const short* WkB  = WB + WK_O;
    const short* WhhB = WB + WHH_O;
    const short* WihB = WB + WIH_O;
    const short* WevB = WB + WEV_O;

    // ---- P0: load h rows, build bf16 copies, zero pad rows
    {
        const int f = t * 4, row = f >> 8, col = f & 255;
        float4 hv = *(const float4*)(h_prev + (size_t)(nb + row) * Dd + col);
        *(float4*)&sH[row][col] = hv;
        bh4 hb4 = { f2bf(hv.x), f2bf(hv.y), f2bf(hv.z), f2bf(hv.w) };
        *(bh4*)(hb + swzH(row, col * 2)) = hb4;
        *(int64_t*)(hb + 4096 + t * 8) = 0;   // sHb rows 8..15
        *(int*)(rb + 2048 + t * 4) = 0;       // sRb rows 8..15
    }
    __syncthreads();

    // ---- P1: k = h @ Wk^T + bk
    {
        const int fr = l & 15, kq = l >> 4, rbase = kq * 4;
        const int colg = wv * 16 + fr;
        f4v acc = {0.f, 0.f, 0.f, 0.f};
#pragma unroll
        for (int kc = 0; kc < 8; ++kc) {
            bh8 a = *(const bh8*)(hb + swzH(fr, kc * 64 + kq * 16));
            bh8 b = *(const bh8*)(WkB + (size_t)colg * 256 + kc * 32 + kq * 8);
            acc = mfma16(a, b, acc);
        }
        if (rbase < 8) {
            const float bs = bk[colg];
#pragma unroll
            for (int rg = 0; rg < 4; ++rg) {
                float x = acc[rg] + bs;
                sK[rbase + rg][colg] = x;
                kout[(size_t)(nb + rbase + rg) * Ff + colg] = x;
            }
        }
    }
    __syncthreads();

    // ---- P2: attention, single pass, fixed-shift softmax (M = beta)
    float invL_r = 0.0f;   // live to P6
    {
        const int half = l >> 5, fl = l & 31, f4 = fl * 4;
        const float* Cn = C + (size_t)(nb + wv) * (Ss * Ff);

        float kv0 = sK[wv][l], kv1 = sK[wv][64 + l];
        float ks = kv0 * kv0 + kv1 * kv1;
#pragma unroll
        for (int o = 32; o > 0; o >>= 1) ks += __shfl_xor(ks, o);
        const float knorm = fmaxf(sqrtf(ks), EPSV);

        float4 hv = *(const float4*)&sH[wv][l * 4];
        float4 wb4 = *(const float4*)(Wb + l * 4);
        float bp = hv.x * wb4.x + hv.y * wb4.y + hv.z * wb4.z + hv.w * wb4.w;
#pragma unroll
        for (int o = 32; o > 0; o >>= 1) bp += __shfl_xor(bp, o);
        bp += bb[0];
        const float beta = ((bp > 20.0f) ? bp : log1pf(__expf(bp))) + 1.0f;

        const float4 kreg = *(const float4*)&sK[wv][f4];
        float lsum = 0.0f;
        f4v racc = {0.f, 0.f, 0.f, 0.f};

#pragma unroll 4
        for (int k = 0; k < 64; ++k) {
            const int s = k * 2 + half;
            const f4v c4 = *(const f4v*)(Cn + (size_t)s * Ff + f4);
            float d = c4.x * kreg.x + c4.y * kreg.y + c4.z * kreg.z + c4.w * kreg.w;
            float q = c4.x * c4.x + c4.y * c4.y + c4.z * c4.z + c4.w * c4.w;
#pragma unroll
            for (int o = 16; o > 0; o >>= 1) {
                d += __shfl_xor(d, o);
                q += __shfl_xor(q, o);
            }
            const float cn = fmaxf(sqrtf(q), EPSV);
            const float x = d / (cn * knorm) * beta;    // x <= beta always
            const float p = __expf(x - beta);
            if (fl == 0) sSc[wv][s] = p;
            lsum += p;
            racc += p * c4;
        }
        const float L = lsum + __shfl_xor(lsum, 32);
        f4v r2;
        r2.x = __shfl_xor(racc.x, 32); r2.y = __shfl_xor(racc.y, 32);
        r2.z = __shfl_xor(racc.z, 32); r2.w = __shfl_xor(racc.w, 32);
        const float iL = 1.0f / L;
        f4v r4 = (racc + r2) * iL;
        if (half == 0) {
            *(f4v*)(rout + (size_t)(nb + wv) * Ff + f4) = r4;
            bh4 rb4 = { f2bf(r4.x), f2bf(r4.y), f2bf(r4.z), f2bf(r4.w) };
            *(bh4*)(rb + swzR(wv, f4 * 2)) = rb4;
        }
        invL_r = iL;
    }
    __syncthreads();

    // ---- P3: gh/gi MFMAs + gates in registers, TWO dp-passes (low VGPR).
    //          Pass dp needs col-tiles i = {dp, 2+dp, 4+dp} (r,z,n gates).
    {
        const int fr = l & 15, kq = l >> 4, rbase = kq * 4;
        float hoReg[2][4];
#pragma unroll
        for (int dp = 0; dp < 2; ++dp) {
            f4v aG[3], aI[3];
#pragma unroll
            for (int gi = 0; gi < 3; ++gi) {
                const int colg = (gi * 2 + dp) * 128 + wv * 16 + fr;
                f4v g = {0.f, 0.f, 0.f, 0.f}, ii = {0.f, 0.f, 0.f, 0.f};
#pragma unroll
                for (int kc = 0; kc < 8; ++kc) {
                    bh8 a = *(const bh8*)(hb + swzH(fr, kc * 64 + kq * 16));
                    bh8 b = *(const bh8*)(WhhB + (size_t)colg * 256 + kc * 32 + kq * 8);
                    g = mfma16(a, b, g);
                }
#pragma unroll
                for (int kc = 0; kc < 4; ++kc) {
                    bh8 a = *(const bh8*)(rb + swzR(fr, kc * 64 + kq * 16));
                    bh8 b = *(const bh8*)(WihB + (size_t)colg * 128 + kc * 32 + kq * 8);
                    ii = mfma16(a, b, ii);
                }
                aG[gi] = g; aI[gi] = ii;
            }
            if (rbase < 8) {
                const int d = dp * 128 + wv * 16 + fr;
                const float br  = bhh[d] + bih[d];
                const float bz  = bhh[256 + d] + bih[256 + d];
                const float bhn = bhh[512 + d];
                const float bin = bih[512 + d];
#pragma unroll
                for (int rg = 0; rg < 4; ++rg) {
                    const float rgt = sigmf(aG[0][rg] + aI[0][rg] + br);
                    const float z   = sigmf(aG[1][rg] + aI[1][rg] + bz);
                    const float nn  = tanhf(aI[2][rg] + bin + rgt * (aG[2][rg] + bhn));
                    const float hp  = sH[rbase + rg][d];
                    hoReg[dp][rg] = (1.0f - z) * nn + z * hp;
                }
            }
        }
        __syncthreads();   // all waves done reading sHb(h) as A-frags
        if (rbase < 8) {
#pragma unroll
            for (int dp = 0; dp < 2; ++dp) {
                const int d = dp * 128 + wv * 16 + fr;
#pragma unroll
                for (int rg = 0; rg < 4; ++rg) {
                    const int row = rbase + rg;
                    const float o = hoReg[dp][rg];
                    ho[(size_t)(nb + row) * Dd + d] = o;
                    *(short*)(hb + row * 512 + ((d * 2) ^ ((row & 7) << 4))) = f2bf(o);
                }
            }
        }
    }
    __syncthreads();

    // ---- P5: [e|v] = h_o @ [We;Wv]^T (+sigmoid on e)
    {
        const int fr = l & 15, kq = l >> 4, rbase = kq * 4;
#pragma unroll
        for (int i = 0; i < 2; ++i) {
            const int colg = i * 128 + wv * 16 + fr;
            f4v acc = {0.f, 0.f, 0.f, 0.f};
#pragma unroll
            for (int kc = 0; kc < 8; ++kc) {
                bh8 a = *(const bh8*)(hb + swzH(fr, kc * 64 + kq * 16));
                bh8 b = *(const bh8*)(WevB + (size_t)colg * 256 + kc * 32 + kq * 8);
                acc = mfma16(a, b, acc);
            }
            if (rbase < 8) {
                const float bs = (colg < 128) ? be[colg] : bv[colg - 128];
#pragma unroll
                for (int rg = 0; rg < 4; ++rg) {
                    float x = acc[rg] + bs;
                    if (colg < 128) x = sigmf(x);
                    sEV[rbase + rg][colg] = x;
                }
            }
        }
    }
    __syncthreads();

    // ---- P6: C_new = C*(1-w*e)+w*v (C re-read L2/L3-hot), NT stores
    {
        const int half = l >> 5, fl = l & 31, f4 = fl * 4;
        const float* Cn = C    + (size_t)(nb + wv) * (Ss * Ff);
        float*       Co = Cnew + (size_t)(nb + wv) * (Ss * Ff);
        const f4v e4 = *(const f4v*)&sEV[wv][f4];
        const f4v v4 = *(const f4v*)&sEV[wv][128 + f4];
        const float iL = invL_r;

#pragma unroll 4
        for (int k = 0; k < 64; ++k) {
            const int s = k * 2 + half;
            const f4v c4 = *(const f4v*)(Cn + (size_t)s * Ff + f4);
            const float wsc = sSc[wv][s] * iL;
            f4v o = c4 * (1.0f - wsc * e4) + wsc * v4;
            __builtin_nontemporal_store(o, (f4v*)(Co + (size_t)s * Ff + f4));
        }
    }
}

// ---------------------------------------------------------------------------
extern "C" void kernel_launch(void* const* d_in, const int* in_sizes, int n_in,
                              void* d_out, int out_size, void* d_ws, size_t ws_size,
                              hipStream_t stream)
{
    const float* h_prev = (const float*)d_in[0];
    const float* C      = (const float*)d_in[1];
    const float* Wk     = (const float*)d_in[2];
    const float* bk     = (const float*)d_in[3];
    const float* Wb     = (const float*)d_in[4];
    const float* bb     = (const float*)d_in[5];
    const float* We     = (const float*)d_in[6];
    const float* be     = (const float*)d_in[7];
    const float* Wv     = (const float*)d_in[8];
    const float* bv     = (const float*)d_in[9];
    const float* Wih    = (const float*)d_in[10];
    const float* Whh    = (const float*)d_in[11];
    const float* bih    = (const float*)d_in[12];
    const float* bhh    = (const float*)d_in[13];

    float* out  = (float*)d_out;
    float* ho   = out + HO_OFF;
    float* Cnew = out + C_OFF;
    float* kbuf = out + K_OFF;
    float* rbuf = out + R_OFF;

    short* wsB = (short*)d_ws;

    prep_weights<<<W_TOT / 256, 256, 0, stream>>>(Wk, Whh, Wih, We, Wv, wsB);

    mega_kernel<<<Nn / 8, 512, 0, stream>>>(
        C, h_prev, wsB, Wb, bb, bk, bhh, bih, be, bv,
        ho, Cnew, kbuf, rbuf);
}

// Round 11
// 220.259 us; speedup vs baseline: 1.0208x; 1.0040x over previous
//
#include <hip/hip_runtime.h>
#include <hip/hip_bf16.h>
#include <cstddef>
#include <cstdint>

// Problem dims
constexpr int Nn = 4096;
constexpr int Ss = 128;
constexpr int Ff = 128;
constexpr int Dd = 256;
constexpr float EPSV = 1e-8f;

// d_out layout (floats): h_o [N*D], C_new [N*S*F], k [N*F], r [N*F]
constexpr size_t HO_OFF = 0;
constexpr size_t C_OFF  = (size_t)Nn * Dd;
constexpr size_t K_OFF  = C_OFF + (size_t)Nn * Ss * Ff;
constexpr size_t R_OFF  = K_OFF + (size_t)Nn * Ff;

typedef __attribute__((ext_vector_type(4))) float f4v;
typedef __attribute__((ext_vector_type(8))) short bh8;
typedef __attribute__((ext_vector_type(4))) short bh4;

// bf16 weight pack offsets in ws (units: shorts)
constexpr int WK_O  = 0;        // Wk   128x256
constexpr int WHH_O = 32768;    // Whh  768x256
constexpr int WIH_O = 229376;   // Wih  768x128
constexpr int WEV_O = 327680;   // [We;Wv] 256x256
constexpr int W_TOT = 393216;

__device__ __forceinline__ float sigmf(float x) { return 1.0f / (1.0f + __expf(-x)); }

__device__ __forceinline__ short f2bf(float x) {
    __hip_bfloat16 h = __float2bfloat16(x);   // RNE
    return *reinterpret_cast<short*>(&h);
}

// XOR swizzle: spread 16B k-slots of row r across banks. Row strides 512B / 256B.
__device__ __forceinline__ int swzH(int row, int kb) { return row * 512 + (kb ^ ((row & 7) << 4)); }
__device__ __forceinline__ int swzR(int row, int kb) { return row * 256 + (kb ^ ((row & 7) << 4)); }

__device__ __forceinline__ f4v mfma16(bh8 a, bh8 b, f4v c) {
    return __builtin_amdgcn_mfma_f32_16x16x32_bf16(a, b, c, 0, 0, 0);
}

// ---------------------------------------------------------------------------
// Prep: convert all weights to bf16, packed row-major into ws.
// ---------------------------------------------------------------------------
__global__ __launch_bounds__(256) void prep_weights(
    const float* __restrict__ Wk, const float* __restrict__ Whh,
    const float* __restrict__ Wih, const float* __restrict__ We,
    const float* __restrict__ Wv, short* __restrict__ out)
{
    int id = blockIdx.x * 256 + threadIdx.x;   // grid covers W_TOT exactly
    float v;
    if      (id < WHH_O) v = Wk[id - WK_O];
    else if (id < WIH_O) v = Whh[id - WHH_O];
    else if (id < WEV_O) v = Wih[id - WIH_O];
    else if (id < WEV_O + 32768) v = We[id - WEV_O];
    else v = Wv[id - WEV_O - 32768];
    out[id] = f2bf(v);
}

// ---------------------------------------------------------------------------
// Mega kernel: 512 blocks x 512 threads; block handles 8 rows, wave w = row w.
//  P0 load h (fp32 + swizzled bf16, zero pads)
//  P1 k = h@Wk^T + bk                          [MFMA]
//  P2a scores LANE-PER-S: lane l owns s=l and s=l+64 fully; C streamed with
//      ZERO cross-lane ops in the loop (k via uniform-address LDS broadcast).
//      One 64-lane reduce per row at the end (for L).
//  P2b r = sum_s p[s]*C[s,:], f-parallel second pass (C L1/L2-hot), shfl-free
//  P3 gh/gi MFMAs in two dp-passes, gates in regs -> h_o
//  P5 [e|v] = sig/lin(h_o@[We;Wv]^T)           [MFMA]
//  P6 C_new = C*(1-w*e)+w*v (C re-read L3-hot), NT stores
// ---------------------------------------------------------------------------
__global__ __launch_bounds__(512, 4) void mega_kernel(
    const float* __restrict__ C, const float* __restrict__ h_prev,
    const short* __restrict__ WB,
    const float* __restrict__ Wb, const float* __restrict__ bb,
    const float* __restrict__ bk, const float* __restrict__ bhh,
    const float* __restrict__ bih, const float* __restrict__ be,
    const float* __restrict__ bv,
    float* __restrict__ ho, float* __restrict__ Cnew,
    float* __restrict__ kout, float* __restrict__ rout)
{
    __shared__ float sH[8][256];                  // h_prev fp32            8 KB
    __shared__ __align__(16) short sHb[16 * 256]; // h/h_o bf16 swizzled    8 KB
    __shared__ __align__(16) short sRb[16 * 128]; // r bf16 swizzled        4 KB
    __shared__ float sK[8][128];                  //                        4 KB
    __shared__ float sSc[8][128];                 // p per (row,s)          4 KB
    __shared__ float sEV[8][256];                 // e | v                  8 KB
                                                  // total 36 KB

    const int t  = threadIdx.x;
    const int l  = t & 63;
    const int wv = t >> 6;
    const int nb = blockIdx.x * 8;
    char* hb = (char*)sHb;
    char* rb = (char*)sRb;

    const short* WkB  = WB + WK_O;
    const short* WhhB = WB + WHH_O;
    const short* WihB = WB + WIH_O;
    const short* WevB = WB + WEV_O;

    // ---- P0: load h rows, build bf16 copies, zero pad rows
    {
        const int f = t * 4, row = f >> 8, col = f & 255;
        float4 hv = *(const float4*)(h_prev + (size_t)(nb + row) * Dd + col);
        *(float4*)&sH[row][col] = hv;
        bh4 hb4 = { f2bf(hv.x), f2bf(hv.y), f2bf(hv.z), f2bf(hv.w) };
        *(bh4*)(hb + swzH(row, col * 2)) = hb4;
        *(int64_t*)(hb + 4096 + t * 8) = 0;   // sHb rows 8..15
        *(int*)(rb + 2048 + t * 4) = 0;       // sRb rows 8..15
    }
    __syncthreads();

    // ---- P1: k = h @ Wk^T + bk
    {
        const int fr = l & 15, kq = l >> 4, rbase = kq * 4;
        const int colg = wv * 16 + fr;
        f4v acc = {0.f, 0.f, 0.f, 0.f};
#pragma unroll
        for (int kc = 0; kc < 8; ++kc) {
            bh8 a = *(const bh8*)(hb + swzH(fr, kc * 64 + kq * 16));
            bh8 b = *(const bh8*)(WkB + (size_t)colg * 256 + kc * 32 + kq * 8);
            acc = mfma16(a, b, acc);
        }
        if (rbase < 8) {
            const float bs = bk[colg];
#pragma unroll
            for (int rg = 0; rg < 4; ++rg) {
                float x = acc[rg] + bs;
                sK[rbase + rg][colg] = x;
                kout[(size_t)(nb + rbase + rg) * Ff + colg] = x;
            }
        }
    }
    __syncthreads();

    // ---- P2: attention. Phase A: lane-per-s scores (no cross-lane in loop).
    float invL_r = 0.0f;   // live to P6
    {
        const float* Cn = C + (size_t)(nb + wv) * (Ss * Ff);

        // knorm (one-time reduce)
        float kv0 = sK[wv][l], kv1 = sK[wv][64 + l];
        float ks = kv0 * kv0 + kv1 * kv1;
#pragma unroll
        for (int o = 32; o > 0; o >>= 1) ks += __shfl_xor(ks, o);
        const float knorm = fmaxf(sqrtf(ks), EPSV);

        // beta (one-time reduce)
        float4 hv = *(const float4*)&sH[wv][l * 4];
        float4 wb4 = *(const float4*)(Wb + l * 4);
        float bp = hv.x * wb4.x + hv.y * wb4.y + hv.z * wb4.z + hv.w * wb4.w;
#pragma unroll
        for (int o = 32; o > 0; o >>= 1) bp += __shfl_xor(bp, o);
        bp += bb[0];
        const float beta = ((bp > 20.0f) ? bp : log1pf(__expf(bp))) + 1.0f;

        // phase A: lane l owns s=l and s=l+64. Streams 2x512B; k broadcast.
        const float* rowA = Cn + (size_t)l * Ff;
        const float* rowB = rowA + 64 * Ff;
        float dA = 0.f, qA = 0.f, dB = 0.f, qB = 0.f;
#pragma unroll 4
        for (int fc = 0; fc < 32; ++fc) {
            const f4v k4 = *(const f4v*)&sK[wv][fc * 4];   // uniform -> broadcast
            const f4v a4 = *(const f4v*)(rowA + fc * 4);
            const f4v b4 = *(const f4v*)(rowB + fc * 4);
            dA += a4.x * k4.x + a4.y * k4.y + a4.z * k4.z + a4.w * k4.w;
            qA += a4.x * a4.x + a4.y * a4.y + a4.z * a4.z + a4.w * a4.w;
            dB += b4.x * k4.x + b4.y * k4.y + b4.z * k4.z + b4.w * k4.w;
            qB += b4.x * b4.x + b4.y * b4.y + b4.z * b4.z + b4.w * b4.w;
        }
        const float xA = dA / (fmaxf(sqrtf(qA), EPSV) * knorm) * beta;
        const float xB = dB / (fmaxf(sqrtf(qB), EPSV) * knorm) * beta;
        const float pA = __expf(xA - beta);     // x <= beta always
        const float pB = __expf(xB - beta);
        sSc[wv][l]      = pA;
        sSc[wv][64 + l] = pB;
        float lsum = pA + pB;
#pragma unroll
        for (int o = 32; o > 0; o >>= 1) lsum += __shfl_xor(lsum, o);
        const float iL = 1.0f / lsum;
        invL_r = iL;

        // phase B: r[f] = sum_s p[s] * C[s][f]; f-parallel, C L1/L2-hot.
        const int half = l >> 5, fl = l & 31, f4 = fl * 4;
        f4v racc = {0.f, 0.f, 0.f, 0.f};
#pragma unroll 4
        for (int k = 0; k < 64; ++k) {
            const int s = k * 2 + half;
            const float p = sSc[wv][s];          // uniform per half -> broadcast
            const f4v c4 = *(const f4v*)(Cn + (size_t)s * Ff + f4);
            racc += p * c4;
        }
        f4v r2;
        r2.x = __shfl_xor(racc.x, 32); r2.y = __shfl_xor(racc.y, 32);
        r2.z = __shfl_xor(racc.z, 32); r2.w = __shfl_xor(racc.w, 32);
        f4v r4 = (racc + r2) * iL;
        if (half == 0) {
            *(f4v*)(rout + (size_t)(nb + wv) * Ff + f4) = r4;
            bh4 rb4 = { f2bf(r4.x), f2bf(r4.y), f2bf(r4.z), f2bf(r4.w) };
            *(bh4*)(rb + swzR(wv, f4 * 2)) = rb4;
        }
    }
    __syncthreads();

    // ---- P3: gh/gi MFMAs + gates in registers, TWO dp-passes (low VGPR).
    {
        const int fr = l & 15, kq = l >> 4, rbase = kq * 4;
        float hoReg[2][4];
#pragma unroll
        for (int dp = 0; dp < 2; ++dp) {
            f4v aG[3], aI[3];
#pragma unroll
            for (int gi = 0; gi < 3; ++gi) {
                const int colg = (gi * 2 + dp) * 128 + wv * 16 + fr;
                f4v g = {0.f, 0.f, 0.f, 0.f}, ii = {0.f, 0.f, 0.f, 0.f};
#pragma unroll
                for (int kc = 0; kc < 8; ++kc) {
                    bh8 a = *(const bh8*)(hb + swzH(fr, kc * 64 + kq * 16));
                    bh8 b = *(const bh8*)(WhhB + (size_t)colg * 256 + kc * 32 + kq * 8);
                    g = mfma16(a, b, g);
                }
#pragma unroll
                for (int kc = 0; kc < 4; ++kc) {
                    bh8 a = *(const bh8*)(rb + swzR(fr, kc * 64 + kq * 16));
                    bh8 b = *(const bh8*)(WihB + (size_t)colg * 128 + kc * 32 + kq * 8);
                    ii = mfma16(a, b, ii);
                }
                aG[gi] = g; aI[gi] = ii;
            }
            if (rbase < 8) {
                const int d = dp * 128 + wv * 16 + fr;
                const float br  = bhh[d] + bih[d];
                const float bz  = bhh[256 + d] + bih[256 + d];
                const float bhn = bhh[512 + d];
                const float bin = bih[512 + d];
#pragma unroll
                for (int rg = 0; rg < 4; ++rg) {
                    const float rgt = sigmf(aG[0][rg] + aI[0][rg] + br);
                    const float z   = sigmf(aG[1][rg] + aI[1][rg] + bz);
                    const float nn  = tanhf(aI[2][rg] + bin + rgt * (aG[2][rg] + bhn));
                    const float hp  = sH[rbase + rg][d];
                    hoReg[dp][rg] = (1.0f - z) * nn + z * hp;
                }
            }
        }
        __syncthreads();   // all waves done reading sHb(h) as A-frags
        if (rbase < 8) {
#pragma unroll
            for (int dp = 0; dp < 2; ++dp) {
                const int d = dp * 128 + wv * 16 + fr;
#pragma unroll
                for (int rg = 0; rg < 4; ++rg) {
                    const int row = rbase + rg;
                    const float o = hoReg[dp][rg];
                    ho[(size_t)(nb + row) * Dd + d] = o;
                    *(short*)(hb + row * 512 + ((d * 2) ^ ((row & 7) << 4))) = f2bf(o);
                }
            }
        }
    }
    __syncthreads();

    // ---- P5: [e|v] = h_o @ [We;Wv]^T (+sigmoid on e)
    {
        const int fr = l & 15, kq = l >> 4, rbase = kq * 4;
#pragma unroll
        for (int i = 0; i < 2; ++i) {
            const int colg = i * 128 + wv * 16 + fr;
            f4v acc = {0.f, 0.f, 0.f, 0.f};
#pragma unroll
            for (int kc = 0; kc < 8; ++kc) {
                bh8 a = *(const bh8*)(hb + swzH(fr, kc * 64 + kq * 16));
                bh8 b = *(const bh8*)(WevB + (size_t)colg * 256 + kc * 32 + kq * 8);
                acc = mfma16(a, b, acc);
            }
            if (rbase < 8) {
                const float bs = (colg < 128) ? be[colg] : bv[colg - 128];
#pragma unroll
                for (int rg = 0; rg < 4; ++rg) {
                    float x = acc[rg] + bs;
                    if (colg < 128) x = sigmf(x);
                    sEV[rbase + rg][colg] = x;
                }
            }
        }
    }
    __syncthreads();

    // ---- P6: C_new = C*(1-w*e)+w*v (C re-read L2/L3-hot), NT stores
    {
        const int half = l >> 5, fl = l & 31, f4 = fl * 4;
        const float* Cn = C    + (size_t)(nb + wv) * (Ss * Ff);
        float*       Co = Cnew + (size_t)(nb + wv) * (Ss * Ff);
        const f4v e4 = *(const f4v*)&sEV[wv][f4];
        const f4v v4 = *(const f4v*)&sEV[wv][128 + f4];
        const float iL = invL_r;

#pragma unroll 4
        for (int k = 0; k < 64; ++k) {
            const int s = k * 2 + half;
            const f4v c4 = *(const f4v*)(Cn + (size_t)s * Ff + f4);
            const float wsc = sSc[wv][s] * iL;
            f4v o = c4 * (1.0f - wsc * e4) + wsc * v4;
            __builtin_nontemporal_store(o, (f4v*)(Co + (size_t)s * Ff + f4));
        }
    }
}

// ---------------------------------------------------------------------------
extern "C" void kernel_launch(void* const* d_in, const int* in_sizes, int n_in,
                              void* d_out, int out_size, void* d_ws, size_t ws_size,
                              hipStream_t stream)
{
    const float* h_prev = (const float*)d_in[0];
    const float* C      = (const float*)d_in[1];
    const float* Wk     = (const float*)d_in[2];
    const float* bk     = (const float*)d_in[3];
    const float* Wb     = (const float*)d_in[4];
    const float* bb     = (const float*)d_in[5];
    const float* We     = (const float*)d_in[6];
    const float* be     = (const float*)d_in[7];
    const float* Wv     = (const float*)d_in[8];
    const float* bv     = (const float*)d_in[9];
    const float* Wih    = (const float*)d_in[10];
    const float* Whh    = (const float*)d_in[11];
    const float* bih    = (const float*)d_in[12];
    const float* bhh    = (const float*)d_in[13];

    float* out  = (float*)d_out;
    float* ho   = out + HO_OFF;
    float* Cnew = out + C_OFF;
    float* kbuf = out + K_OFF;
    float* rbuf = out + R_OFF;

    short* wsB = (short*)d_ws;

    prep_weights<<<W_TOT / 256, 256, 0, stream>>>(Wk, Whh, Wih, We, Wv, wsB);

    mega_kernel<<<Nn / 8, 512, 0, stream>>>(
        C, h_prev, wsB, Wb, bb, bk, bhh, bih, be, bv,
        ho, Cnew, kbuf, rbuf);
}

// Round 12
// 192.850 us; speedup vs baseline: 1.1658x; 1.1421x over previous
//
#include <hip/hip_runtime.h>
#include <hip/hip_bf16.h>
#include <cstddef>
#include <cstdint>

// Problem dims
constexpr int Nn = 4096;
constexpr int Ss = 128;
constexpr int Ff = 128;
constexpr int Dd = 256;
constexpr float EPSV = 1e-8f;

// d_out layout (floats): h_o [N*D], C_new [N*S*F], k [N*F], r [N*F]
constexpr size_t HO_OFF = 0;
constexpr size_t C_OFF  = (size_t)Nn * Dd;
constexpr size_t K_OFF  = C_OFF + (size_t)Nn * Ss * Ff;
constexpr size_t R_OFF  = K_OFF + (size_t)Nn * Ff;

typedef __attribute__((ext_vector_type(4))) float f4v;
typedef __attribute__((ext_vector_type(8))) short bh8;
typedef __attribute__((ext_vector_type(4))) short bh4;

// bf16 weight pack offsets in ws (units: shorts)
constexpr int WK_O  = 0;        // Wk   128x256
constexpr int WHH_O = 32768;    // Whh  768x256
constexpr int WIH_O = 229376;   // Wih  768x128
constexpr int WEV_O = 327680;   // [We;Wv] 256x256
constexpr int W_TOT = 393216;

__device__ __forceinline__ float sigmf(float x) { return 1.0f / (1.0f + __expf(-x)); }

__device__ __forceinline__ short f2bf(float x) {
    __hip_bfloat16 h = __float2bfloat16(x);   // RNE
    return *reinterpret_cast<short*>(&h);
}

// XOR swizzle: spread 16B k-slots of row r across banks. Row strides 512B / 256B.
__device__ __forceinline__ int swzH(int row, int kb) { return row * 512 + (kb ^ ((row & 7) << 4)); }
__device__ __forceinline__ int swzR(int row, int kb) { return row * 256 + (kb ^ ((row & 7) << 4)); }

__device__ __forceinline__ f4v mfma16(bh8 a, bh8 b, f4v c) {
    return __builtin_amdgcn_mfma_f32_16x16x32_bf16(a, b, c, 0, 0, 0);
}

// ---------------------------------------------------------------------------
// Prep: convert all weights to bf16, packed row-major into ws.
// ---------------------------------------------------------------------------
__global__ __launch_bounds__(256) void prep_weights(
    const float* __restrict__ Wk, const float* __restrict__ Whh,
    const float* __restrict__ Wih, const float* __restrict__ We,
    const float* __restrict__ Wv, short* __restrict__ out)
{
    int id = blockIdx.x * 256 + threadIdx.x;   // grid covers W_TOT exactly
    float v;
    if      (id < WHH_O) v = Wk[id - WK_O];
    else if (id < WIH_O) v = Whh[id - WHH_O];
    else if (id < WEV_O) v = Wih[id - WIH_O];
    else if (id < WEV_O + 32768) v = We[id - WEV_O];
    else v = Wv[id - WEV_O - 32768];
    out[id] = f2bf(v);
}

// ---------------------------------------------------------------------------
// Mega kernel: 512 blocks x 512 threads; block handles 8 rows, wave w = row w.
//  P0 load h (fp32 + swizzled bf16, zero pads)
//  P1 k = h@Wk^T + bk                          [MFMA]
//  P2 attention TILED: for each 16-row tile (8KB, fits L1):
//       A: scores, 4 lanes/row (2 shfls only), fixed-shift p=exp(x-beta)
//       B: r partial, f-parallel re-read of the SAME tile from L1
//     -> C read from HBM exactly once in P2; no long shfl chains
//  P3 gh/gi MFMAs in two dp-passes, gates in regs -> h_o
//  P5 [e|v] = sig/lin(h_o@[We;Wv]^T)           [MFMA]
//  P6 C_new = C*(1-w*e)+w*v (C re-read L3-hot), NT stores
// ---------------------------------------------------------------------------
__global__ __launch_bounds__(512, 4) void mega_kernel(
    const float* __restrict__ C, const float* __restrict__ h_prev,
    const short* __restrict__ WB,
    const float* __restrict__ Wb, const float* __restrict__ bb,
    const float* __restrict__ bk, const float* __restrict__ bhh,
    const float* __restrict__ bih, const float* __restrict__ be,
    const float* __restrict__ bv,
    float* __restrict__ ho, float* __restrict__ Cnew,
    float* __restrict__ kout, float* __restrict__ rout)
{
    __shared__ float sH[8][256];                  // h_prev fp32            8 KB
    __shared__ __align__(16) short sHb[16 * 256]; // h/h_o bf16 swizzled    8 KB
    __shared__ __align__(16) short sRb[16 * 128]; // r bf16 swizzled        4 KB
    __shared__ float sK[8][128];                  //                        4 KB
    __shared__ float sSc[8][128];                 // p per (row,s)          4 KB
    __shared__ float sEV[8][256];                 // e | v                  8 KB
                                                  // total 36 KB

    const int t  = threadIdx.x;
    const int l  = t & 63;
    const int wv = t >> 6;
    const int nb = blockIdx.x * 8;
    char* hb = (char*)sHb;
    char* rb = (char*)sRb;

    const short* WkB  = WB + WK_O;
    const short* WhhB = WB + WHH_O;
    const short* WihB = WB + WIH_O;
    const short* WevB = WB + WEV_O;

    // ---- P0: load h rows, build bf16 copies, zero pad rows
    {
        const int f = t * 4, row = f >> 8, col = f & 255;
        float4 hv = *(const float4*)(h_prev + (size_t)(nb + row) * Dd + col);
        *(float4*)&sH[row][col] = hv;
        bh4 hb4 = { f2bf(hv.x), f2bf(hv.y), f2bf(hv.z), f2bf(hv.w) };
        *(bh4*)(hb + swzH(row, col * 2)) = hb4;
        *(int64_t*)(hb + 4096 + t * 8) = 0;   // sHb rows 8..15
        *(int*)(rb + 2048 + t * 4) = 0;       // sRb rows 8..15
    }
    __syncthreads();

    // ---- P1: k = h @ Wk^T + bk
    {
        const int fr = l & 15, kq = l >> 4, rbase = kq * 4;
        const int colg = wv * 16 + fr;
        f4v acc = {0.f, 0.f, 0.f, 0.f};
#pragma unroll
        for (int kc = 0; kc < 8; ++kc) {
            bh8 a = *(const bh8*)(hb + swzH(fr, kc * 64 + kq * 16));
            bh8 b = *(const bh8*)(WkB + (size_t)colg * 256 + kc * 32 + kq * 8);
            acc = mfma16(a, b, acc);
        }
        if (rbase < 8) {
            const float bs = bk[colg];
#pragma unroll
            for (int rg = 0; rg < 4; ++rg) {
                float x = acc[rg] + bs;
                sK[rbase + rg][colg] = x;
                kout[(size_t)(nb + rbase + rg) * Ff + colg] = x;
            }
        }
    }
    __syncthreads();

    // ---- P2: attention, tiled A/B (tile = 16 s-rows = 8KB, L1-resident)
    float invL_r = 0.0f;   // live to P6
    {
        const float* Cn = C + (size_t)(nb + wv) * (Ss * Ff);

        // knorm (one-time reduce)
        float kv0 = sK[wv][l], kv1 = sK[wv][64 + l];
        float ks = kv0 * kv0 + kv1 * kv1;
#pragma unroll
        for (int o = 32; o > 0; o >>= 1) ks += __shfl_xor(ks, o);
        const float knorm = fmaxf(sqrtf(ks), EPSV);

        // beta (one-time reduce)
        float4 hv = *(const float4*)&sH[wv][l * 4];
        float4 wb4 = *(const float4*)(Wb + l * 4);
        float bp = hv.x * wb4.x + hv.y * wb4.y + hv.z * wb4.z + hv.w * wb4.w;
#pragma unroll
        for (int o = 32; o > 0; o >>= 1) bp += __shfl_xor(bp, o);
        bp += bb[0];
        const float beta = ((bp > 20.0f) ? bp : log1pf(__expf(bp))) + 1.0f;
        const float bOkn = beta / knorm;

        const int qrow = l >> 2;            // phase A: row within tile
        const int subf = l & 3;             // phase A: f-quarter
        const int half = l >> 5, fl = l & 31, f4 = fl * 4;
        float lsum = 0.0f;
        f4v racc = {0.f, 0.f, 0.f, 0.f};

#pragma unroll 1
        for (int tile = 0; tile < 8; ++tile) {
            const int s0 = tile * 16;
            // --- phase A: scores for rows s0..s0+15 (4 lanes per row)
            const float* rowp = Cn + (size_t)(s0 + qrow) * Ff + subf * 32;
            float d = 0.f, q = 0.f;
#pragma unroll
            for (int fc = 0; fc < 8; ++fc) {
                const f4v c4 = *(const f4v*)(rowp + fc * 4);
                const f4v k4 = *(const f4v*)&sK[wv][subf * 32 + fc * 4];
                d += c4.x * k4.x + c4.y * k4.y + c4.z * k4.z + c4.w * k4.w;
                q += c4.x * c4.x + c4.y * c4.y + c4.z * c4.z + c4.w * c4.w;
            }
            d += __shfl_xor(d, 1); d += __shfl_xor(d, 2);
            q += __shfl_xor(q, 1); q += __shfl_xor(q, 2);
            const float x = d / fmaxf(sqrtf(q), EPSV) * bOkn;   // <= beta
            const float p = __expf(x - beta);
            if (subf == 0) sSc[wv][s0 + qrow] = p;
            lsum += p;                       // each row counted 4x; fix later
            // --- phase B: r partial over the same tile (L1-hot), f-parallel
#pragma unroll
            for (int j = 0; j < 8; ++j) {
                const int s = s0 + j * 2 + half;
                const float pp = sSc[wv][s];
                const f4v c4 = *(const f4v*)(Cn + (size_t)s * Ff + f4);
                racc += pp * c4;
            }
        }
#pragma unroll
        for (int o = 32; o > 0; o >>= 1) lsum += __shfl_xor(lsum, o);
        const float iL = 4.0f / lsum;        // rows counted 4x in lsum
        invL_r = iL;

        f4v r2;
        r2.x = __shfl_xor(racc.x, 32); r2.y = __shfl_xor(racc.y, 32);
        r2.z = __shfl_xor(racc.z, 32); r2.w = __shfl_xor(racc.w, 32);
        f4v r4 = (racc + r2) * iL;
        if (half == 0) {
            *(f4v*)(rout + (size_t)(nb + wv) * Ff + f4) = r4;
            bh4 rb4 = { f2bf(r4.x), f2bf(r4.y), f2bf(r4.z), f2bf(r4.w) };
            *(bh4*)(rb + swzR(wv, f4 * 2)) = rb4;
        }
    }
    __syncthreads();

    // ---- P3: gh/gi MFMAs + gates in registers, TWO dp-passes (low VGPR).
    {
        const int fr = l & 15, kq = l >> 4, rbase = kq * 4;
        float hoReg[2][4];
#pragma unroll
        for (int dp = 0; dp < 2; ++dp) {
            f4v aG[3], aI[3];
#pragma unroll
            for (int gi = 0; gi < 3; ++gi) {
                const int colg = (gi * 2 + dp) * 128 + wv * 16 + fr;
                f4v g = {0.f, 0.f, 0.f, 0.f}, ii = {0.f, 0.f, 0.f, 0.f};
#pragma unroll
                for (int kc = 0; kc < 8; ++kc) {
                    bh8 a = *(const bh8*)(hb + swzH(fr, kc * 64 + kq * 16));
                    bh8 b = *(const bh8*)(WhhB + (size_t)colg * 256 + kc * 32 + kq * 8);
                    g = mfma16(a, b, g);
                }
#pragma unroll
                for (int kc = 0; kc < 4; ++kc) {
                    bh8 a = *(const bh8*)(rb + swzR(fr, kc * 64 + kq * 16));
                    bh8 b = *(const bh8*)(WihB + (size_t)colg * 128 + kc * 32 + kq * 8);
                    ii = mfma16(a, b, ii);
                }
                aG[gi] = g; aI[gi] = ii;
            }
            if (rbase < 8) {
                const int d = dp * 128 + wv * 16 + fr;
                const float br  = bhh[d] + bih[d];
                const float bz  = bhh[256 + d] + bih[256 + d];
                const float bhn = bhh[512 + d];
                const float bin = bih[512 + d];
#pragma unroll
                for (int rg = 0; rg < 4; ++rg) {
                    const float rgt = sigmf(aG[0][rg] + aI[0][rg] + br);
                    const float z   = sigmf(aG[1][rg] + aI[1][rg] + bz);
                    const float nn  = tanhf(aI[2][rg] + bin + rgt * (aG[2][rg] + bhn));
                    const float hp  = sH[rbase + rg][d];
                    hoReg[dp][rg] = (1.0f - z) * nn + z * hp;
                }
            }
        }
        __syncthreads();   // all waves done reading sHb(h) as A-frags
        if (rbase < 8) {
#pragma unroll
            for (int dp = 0; dp < 2; ++dp) {
                const int d = dp * 128 + wv * 16 + fr;
#pragma unroll
                for (int rg = 0; rg < 4; ++rg) {
                    const int row = rbase + rg;
                    const float o = hoReg[dp][rg];
                    ho[(size_t)(nb + row) * Dd + d] = o;
                    *(short*)(hb + row * 512 + ((d * 2) ^ ((row & 7) << 4))) = f2bf(o);
                }
            }
        }
    }
    __syncthreads();

    // ---- P5: [e|v] = h_o @ [We;Wv]^T (+sigmoid on e)
    {
        const int fr = l & 15, kq = l >> 4, rbase = kq * 4;
#pragma unroll
        for (int i = 0; i < 2; ++i) {
            const int colg = i * 128 + wv * 16 + fr;
            f4v acc = {0.f, 0.f, 0.f, 0.f};
#pragma unroll
            for (int kc = 0; kc < 8; ++kc) {
                bh8 a = *(const bh8*)(hb + swzH(fr, kc * 64 + kq * 16));
                bh8 b = *(const bh8*)(WevB + (size_t)colg * 256 + kc * 32 + kq * 8);
                acc = mfma16(a, b, acc);
            }
            if (rbase < 8) {
                const float bs = (colg < 128) ? be[colg] : bv[colg - 128];
#pragma unroll
                for (int rg = 0; rg < 4; ++rg) {
                    float x = acc[rg] + bs;
                    if (colg < 128) x = sigmf(x);
                    sEV[rbase + rg][colg] = x;
                }
            }
        }
    }
    __syncthreads();

    // ---- P6: C_new = C*(1-w*e)+w*v (C re-read L2/L3-hot), NT stores
    {
        const int half = l >> 5, fl = l & 31, f4 = fl * 4;
        const float* Cn = C    + (size_t)(nb + wv) * (Ss * Ff);
        float*       Co = Cnew + (size_t)(nb + wv) * (Ss * Ff);
        const f4v e4 = *(const f4v*)&sEV[wv][f4];
        const f4v v4 = *(const f4v*)&sEV[wv][128 + f4];
        const float iL = invL_r;

#pragma unroll 4
        for (int k = 0; k < 64; ++k) {
            const int s = k * 2 + half;
            const f4v c4 = *(const f4v*)(Cn + (size_t)s * Ff + f4);
            const float wsc = sSc[wv][s] * iL;
            f4v o = c4 * (1.0f - wsc * e4) + wsc * v4;
            __builtin_nontemporal_store(o, (f4v*)(Co + (size_t)s * Ff + f4));
        }
    }
}

// ---------------------------------------------------------------------------
extern "C" void kernel_launch(void* const* d_in, const int* in_sizes, int n_in,
                              void* d_out, int out_size, void* d_ws, size_t ws_size,
                              hipStream_t stream)
{
    const float* h_prev = (const float*)d_in[0];
    const float* C      = (const float*)d_in[1];
    const float* Wk     = (const float*)d_in[2];
    const float* bk     = (const float*)d_in[3];
    const float* Wb     = (const float*)d_in[4];
    const float* bb     = (const float*)d_in[5];
    const float* We     = (const float*)d_in[6];
    const float* be     = (const float*)d_in[7];
    const float* Wv     = (const float*)d_in[8];
    const float* bv     = (const float*)d_in[9];
    const float* Wih    = (const float*)d_in[10];
    const float* Whh    = (const float*)d_in[11];
    const float* bih    = (const float*)d_in[12];
    const float* bhh    = (const float*)d_in[13];

    float* out  = (float*)d_out;
    float* ho   = out + HO_OFF;
    float* Cnew = out + C_OFF;
    float* kbuf = out + K_OFF;
    float* rbuf = out + R_OFF;

    short* wsB = (short*)d_ws;

    prep_weights<<<W_TOT / 256, 256, 0, stream>>>(Wk, Whh, Wih, We, Wv, wsB);

    mega_kernel<<<Nn / 8, 512, 0, stream>>>(
        C, h_prev, wsB, Wb, bb, bk, bhh, bih, be, bv,
        ho, Cnew, kbuf, rbuf);
}